// Round 6
// baseline (1612.241 us; speedup 1.0000x reference)
//
#include <hip/hip_runtime.h>
#include <hip/hip_bf16.h>
#include <cstdint>
#include <cmath>

typedef __bf16 bf16;
typedef __attribute__((ext_vector_type(8))) __bf16 bf16x8;
typedef __attribute__((ext_vector_type(4))) __bf16 bf16x4;
typedef __attribute__((ext_vector_type(4))) float f32x4;

// async global->LDS, 16B per lane, dest = wave-uniform base (+ lane*16 by HW)
__device__ __forceinline__ void gload_lds16(const void* g, void* l) {
  __builtin_amdgcn_global_load_lds((__attribute__((address_space(1))) void*)g,
                                   (__attribute__((address_space(3))) void*)l,
                                   16, 0, 0);
}

// ---------------------------------------------------------------------------
// Fat-wave drift GEMM: BM x 256 tile, BK=64, 4 waves (2M x 2N: wave = BM/2
// rows x 128 cols), double-buffered LDS, ONE __syncthreads per K-tile,
// full-tile prefetch front-loaded. C = A[M,K] @ Bt^T (Bt stored [N][K] bf16).
// Per K-tile per wave: 2 ks half-steps of {16 ds_read_b128 -> 64 MFMA} so the
// LDS port time (1024 cyc/CU) hides under the MFMA stream (2483 cyc/SIMD).
// LDS: buf*BUFS + {A:0,B:ASZ} + row*128 + (chunk^(row&7))*16 (conflict-free).
// EPI 1: f32 = acc+bias[col]+resid       (Wo)
// EPI 2: f32 = acc+resid                 (W3)
// EPI 3: QKV fused RoPE + head reorder: q,k -> [h][s][128], v -> [h][128][s]
// EPI 4: FF fused SwiGLU on 16-interleaved W1/W2 -> g [s][11008]
// ---------------------------------------------------------------------------
template<int BM, int EPI>
__global__ __launch_bounds__(256, 1) void gemmd(
    const bf16* __restrict__ A, const bf16* __restrict__ Bt, void* __restrict__ Cv,
    const float* __restrict__ bias, const float* __restrict__ resid,
    const float* __restrict__ cosT, const float* __restrict__ sinT,
    bf16* __restrict__ q_out, bf16* __restrict__ k_out, bf16* __restrict__ v_out,
    int M, int N, int K, int gm) {
  extern __shared__ char lds[];
  constexpr int ASZ = BM * 128;      // A region bytes (BM rows x 128B)
  constexpr int BUFS = ASZ + 32768;  // per-buffer stride (B = 256 rows x 128B)
  constexpr int MF = BM / 32;        // m-frags per wave (wave rows = BM/2)
  constexpr int LA = BM / 32;        // A stage loads per thread

  const int tid = threadIdx.x;
  const int wave = tid >> 6, lane = tid & 63;
  const int wr = wave >> 1, wc = wave & 1;   // 2M x 2N wave grid
  const int l15 = lane & 15, l4 = lane >> 4;
  // XCD-aware swizzle (grids are multiples of 8)
  const int qq = gridDim.x >> 3;
  const int wgid = (blockIdx.x & 7) * qq + (blockIdx.x >> 3);
  const int tm = wgid % gm, tn = wgid / gm;
  const long brow = (long)tm * BM, bcol = (long)tn * 256;
  const int NT = K >> 6;
  const bf16* Ab = A + brow * K;
  const bf16* Bb = Bt + bcol * K;

  f32x4 acc[MF][8];
  #pragma unroll
  for (int i = 0; i < MF; ++i)
    #pragma unroll
    for (int j = 0; j < 8; ++j) acc[i][j] = (f32x4){0.f, 0.f, 0.f, 0.f};

  bf16x8 a[MF], b[8];

  auto stage = [&](int T) {
    const long kofs = (long)T << 6;
    char* wb = lds + (T & 1) * BUFS;
    #pragma unroll
    for (int i = 0; i < LA; ++i) {
      const int slot = i * 256 + tid, r = slot >> 3, c0 = slot & 7;
      gload_lds16(Ab + (long)r * K + kofs + ((c0 ^ (r & 7)) << 3), wb + slot * 16);
    }
    #pragma unroll
    for (int i = 0; i < 8; ++i) {
      const int slot = i * 256 + tid, r = slot >> 3, c0 = slot & 7;
      gload_lds16(Bb + (long)r * K + kofs + ((c0 ^ (r & 7)) << 3), wb + ASZ + slot * 16);
    }
  };

  stage(0);
  __syncthreads();

  for (int g = 0; g < NT; ++g) {
    const int pg = (g & 1) * BUFS;
    if (g + 1 < NT) stage(g + 1);   // writes opposite buffer; fenced by barrier
    #pragma unroll
    for (int ks = 0; ks < 2; ++ks) {
      #pragma unroll
      for (int nf = 0; nf < 8; ++nf) {
        const int r = wc * 128 + nf * 16 + l15;
        b[nf] = *(const bf16x8*)(lds + pg + ASZ + r * 128 + (((ks * 4 + l4) ^ (r & 7)) << 4));
      }
      #pragma unroll
      for (int mf = 0; mf < MF; ++mf) {
        const int r = wr * (BM / 2) + mf * 16 + l15;
        a[mf] = *(const bf16x8*)(lds + pg + r * 128 + (((ks * 4 + l4) ^ (r & 7)) << 4));
      }
      #pragma unroll
      for (int mf = 0; mf < MF; ++mf)
        #pragma unroll
        for (int nf = 0; nf < 8; ++nf)
          acc[mf][nf] = __builtin_amdgcn_mfma_f32_16x16x32_bf16(
              a[mf], b[nf], acc[mf][nf], 0, 0, 0);
    }
    __syncthreads();
  }

  // ------------------------------- epilogues -------------------------------
  if (EPI == 1 || EPI == 2) {
    #pragma unroll
    for (int mf = 0; mf < MF; ++mf) {
      const long row0 = brow + wr * (BM / 2) + mf * 16 + l4 * 4;
      #pragma unroll
      for (int nf = 0; nf < 8; ++nf) {
        const long col = bcol + wc * 128 + nf * 16 + l15;
        #pragma unroll
        for (int rj = 0; rj < 4; ++rj) {
          const long idx = (row0 + rj) * N + col;
          const float v = acc[mf][nf][rj];
          if (EPI == 1) ((float*)Cv)[idx] = v + bias[col] + resid[idx];
          else          ((float*)Cv)[idx] = v + resid[idx];
        }
      }
    }
  } else if (EPI == 3) {
    const int region = (int)(bcol >> 12);           // 0=Q, 1=K, 2=V
    const int hc = (int)(bcol & 4095) + wc * 128;   // head-space col base
    const int h = hc >> 7;
    if (region < 2) {
      bf16* dh = (region == 0 ? q_out : k_out) + (long)h * 2048 * 128;
      #pragma unroll
      for (int mf = 0; mf < MF; ++mf) {
        #pragma unroll
        for (int rj = 0; rj < 4; ++rj) {
          const int s = (int)brow + wr * (BM / 2) + mf * 16 + l4 * 4 + rj;
          const float* cr = cosT + s * 64;
          const float* sr = sinT + s * 64;
          #pragma unroll
          for (int nfp = 0; nfp < 4; ++nfp) {
            const int d = nfp * 16 + l15;
            const float c = cr[d], sn = sr[d];
            const float x1 = acc[mf][nfp][rj], x2 = acc[mf][nfp + 4][rj];
            dh[(long)s * 128 + d]      = (bf16)(x1 * c - x2 * sn);
            dh[(long)s * 128 + d + 64] = (bf16)(x2 * c + x1 * sn);
          }
        }
      }
    } else {
      bf16* dh = v_out + (long)h * 128 * 2048;
      #pragma unroll
      for (int mf = 0; mf < MF; ++mf) {
        const int s0 = (int)brow + wr * (BM / 2) + mf * 16 + l4 * 4;
        #pragma unroll
        for (int nf = 0; nf < 8; ++nf) {
          const int d = nf * 16 + l15;
          bf16x4 v;
          #pragma unroll
          for (int rj = 0; rj < 4; ++rj) v[rj] = (bf16)acc[mf][nf][rj];
          *(bf16x4*)(dh + (long)d * 2048 + s0) = v;
        }
      }
    }
  } else {  // EPI == 4: fused SwiGLU, interleaved W12 columns -> g [s][11008]
    #pragma unroll
    for (int mf = 0; mf < MF; ++mf) {
      #pragma unroll
      for (int rj = 0; rj < 4; ++rj) {
        const int s = (int)brow + wr * (BM / 2) + mf * 16 + l4 * 4 + rj;
        bf16* gr = (bf16*)Cv + (long)s * 11008;
        #pragma unroll
        for (int nfp = 0; nfp < 4; ++nfp) {
          const int col = (int)bcol + wc * 128 + nfp * 32 + l15;
          const int j = ((col >> 5) << 4) + l15;
          const float x1 = acc[mf][2 * nfp][rj], x2 = acc[mf][2 * nfp + 1][rj];
          const float sg = x1 / (1.f + __expf(-x1));
          gr[j] = (bf16)(sg * x2);
        }
      }
    }
  }
}

// ---------------------------------------------------------------------------
// RMSNorm: one block per row of [2048][4096] f32 -> bf16
// ---------------------------------------------------------------------------
__global__ __launch_bounds__(256) void rmsnorm_kernel(
    const float* __restrict__ X, const float* __restrict__ gamma,
    bf16* __restrict__ out, int D) {
  const int row = blockIdx.x;
  const float* xr = X + (long)row * D;
  float ss = 0.f;
  for (int i = threadIdx.x * 4; i < D; i += 1024) {
    float4 v = *(const float4*)(xr + i);
    ss += v.x * v.x + v.y * v.y + v.z * v.z + v.w * v.w;
  }
  #pragma unroll
  for (int off = 32; off; off >>= 1) ss += __shfl_down(ss, off, 64);
  __shared__ float wsum[4];
  if ((threadIdx.x & 63) == 0) wsum[threadIdx.x >> 6] = ss;
  __syncthreads();
  const float tot = wsum[0] + wsum[1] + wsum[2] + wsum[3];
  const float scale = rsqrtf(1e-7f + tot / (float)D);
  bf16* orow = out + (long)row * D;
  for (int i = threadIdx.x * 4; i < D; i += 1024) {
    float4 v = *(const float4*)(xr + i);
    float4 g = *(const float4*)(gamma + i);
    orow[i]     = (bf16)(v.x * scale * g.x);
    orow[i + 1] = (bf16)(v.y * scale * g.y);
    orow[i + 2] = (bf16)(v.z * scale * g.z);
    orow[i + 3] = (bf16)(v.w * scale * g.w);
  }
}

// ---------------------------------------------------------------------------
// Weight transpose + f32->bf16: in [R][C] f32 -> out [C][R] bf16. 64x64 tiles.
// ---------------------------------------------------------------------------
__global__ __launch_bounds__(256) void wtrans_kernel(
    const float* __restrict__ in, bf16* __restrict__ out, int R, int C) {
  __shared__ float t[64][65];
  const int bx = blockIdx.x, by = blockIdx.y;
  const int tx = threadIdx.x & 63, ty = threadIdx.x >> 6;  // 64 x 4
  #pragma unroll
  for (int i = 0; i < 64; i += 4)
    t[ty + i][tx] = in[(long)(by * 64 + ty + i) * C + bx * 64 + tx];
  __syncthreads();
  #pragma unroll
  for (int i = 0; i < 64; i += 4)
    out[(long)(bx * 64 + ty + i) * R + by * 64 + tx] = (bf16)t[tx][ty + i];
}

// ---------------------------------------------------------------------------
// W1/W2 interleaved transpose: in [4096][11008] f32, source col j ->
// out row ((j>>4)<<5) + off + (j&15)  (off: W1=0, W2=16), cols = k (4096 bf16)
// ---------------------------------------------------------------------------
__global__ __launch_bounds__(256) void w12trans_kernel(
    const float* __restrict__ in, bf16* __restrict__ out, int off) {
  __shared__ float t[32][33];
  const int bx = blockIdx.x, by = blockIdx.y;  // bx: j-tiles (344), by: k (128)
  const int tx = threadIdx.x & 31, ty = threadIdx.x >> 5;
  #pragma unroll
  for (int i = 0; i < 32; i += 8)
    t[ty + i][tx] = in[(long)(by * 32 + ty + i) * 11008 + bx * 32 + tx];
  __syncthreads();
  #pragma unroll
  for (int i = 0; i < 32; i += 8) {
    const int j = bx * 32 + ty + i;
    const int r = ((j >> 4) << 5) + off + (j & 15);
    out[(long)r * 4096 + by * 32 + tx] = (bf16)t[tx][ty + i];
  }
}

// ---------------------------------------------------------------------------
__global__ __launch_bounds__(256) void rope_table_kernel(float* __restrict__ cosT,
                                                         float* __restrict__ sinT) {
  const int idx = blockIdx.x * 256 + threadIdx.x;
  const int i = idx & 63, s = idx >> 6;
  const float inv = powf(10000.f, -(float)i / 64.f);
  const float ang = (float)s * inv;
  cosT[idx] = cosf(ang);
  sinT[idx] = sinf(ang);
}

// ---------------------------------------------------------------------------
// Flash attention, causal. Block=(qb,head), 4 waves x 16 q-rows.
// ---------------------------------------------------------------------------
__global__ __launch_bounds__(256) void attn_kernel(
    const bf16* __restrict__ qh, const bf16* __restrict__ kh,
    const bf16* __restrict__ vt, bf16* __restrict__ outb) {
  constexpr int S = 2048;
  const int qb = blockIdx.x, head = blockIdx.y;
  const int tid = threadIdx.x, wave = tid >> 6, lane = tid & 63;
  __shared__ bf16 Ks[64 * 128];
  __shared__ bf16 Vs[128 * 64];
  __shared__ bf16 Plds[4][16 * 64];
  const bf16* qhh = qh + (long)head * S * 128;
  const bf16* khh = kh + (long)head * S * 128;
  const bf16* vth = vt + (long)head * 128 * S;

  const int l15 = lane & 15, l4 = lane >> 4;
  const int qrow = qb * 64 + wave * 16 + l15;
  bf16x8 qf[4];
  #pragma unroll
  for (int kf = 0; kf < 4; ++kf)
    qf[kf] = *(const bf16x8*)(qhh + (long)qrow * 128 + kf * 32 + l4 * 8);

  float m_r[4], l_r[4];
  #pragma unroll
  for (int r = 0; r < 4; ++r) { m_r[r] = -INFINITY; l_r[r] = 0.f; }
  f32x4 oacc[8] = {};
  const float scale = 0.08838834764831845f;

  for (int tb = 0; tb <= qb; ++tb) {
    #pragma unroll
    for (int i = 0; i < 4; ++i) {
      const int c = wave + 4 * i;
      gload_lds16(khh + (long)(tb * 64 + c * 4 + l4) * 128 + l15 * 8, Ks + c * 512);
      gload_lds16(vth + (long)(c * 8 + (lane >> 3)) * S + tb * 64 + (lane & 7) * 8, Vs + c * 512);
    }
    __syncthreads();

    f32x4 sf[4];
    #pragma unroll
    for (int ft = 0; ft < 4; ++ft) {
      f32x4 acn = {};
      #pragma unroll
      for (int kf = 0; kf < 4; ++kf) {
        bf16x8 kfr = *(const bf16x8*)(Ks + (ft * 16 + l15) * 128 + kf * 32 + l4 * 8);
        acn = __builtin_amdgcn_mfma_f32_16x16x32_bf16(qf[kf], kfr, acn, 0, 0, 0);
      }
      #pragma unroll
      for (int r = 0; r < 4; ++r) sf[ft][r] = acn[r] * scale;
    }
    if (tb == qb) {
      #pragma unroll
      for (int ft = 0; ft < 4; ++ft) {
        const int t_l = ft * 16 + l15;
        #pragma unroll
        for (int r = 0; r < 4; ++r)
          if (t_l > wave * 16 + l4 * 4 + r) sf[ft][r] = -INFINITY;
      }
    }
    float scl[4];
    #pragma unroll
    for (int r = 0; r < 4; ++r) {
      float mx = fmaxf(fmaxf(sf[0][r], sf[1][r]), fmaxf(sf[2][r], sf[3][r]));
      mx = fmaxf(mx, __shfl_xor(mx, 1, 64));
      mx = fmaxf(mx, __shfl_xor(mx, 2, 64));
      mx = fmaxf(mx, __shfl_xor(mx, 4, 64));
      mx = fmaxf(mx, __shfl_xor(mx, 8, 64));
      const float mnew = fmaxf(m_r[r], mx);
      scl[r] = __expf(m_r[r] - mnew);
      m_r[r] = mnew;
      float rs = 0.f;
      #pragma unroll
      for (int ft = 0; ft < 4; ++ft) {
        const float pexp = __expf(sf[ft][r] - mnew);
        sf[ft][r] = pexp;
        rs += pexp;
      }
      rs += __shfl_xor(rs, 1, 64);
      rs += __shfl_xor(rs, 2, 64);
      rs += __shfl_xor(rs, 4, 64);
      rs += __shfl_xor(rs, 8, 64);
      l_r[r] = l_r[r] * scl[r] + rs;
    }
    #pragma unroll
    for (int ft = 0; ft < 4; ++ft)
      #pragma unroll
      for (int r = 0; r < 4; ++r)
        Plds[wave][(l4 * 4 + r) * 64 + ft * 16 + l15] = (bf16)sf[ft][r];
    #pragma unroll
    for (int fd = 0; fd < 8; ++fd)
      #pragma unroll
      for (int r = 0; r < 4; ++r) oacc[fd][r] *= scl[r];
    #pragma unroll
    for (int fd = 0; fd < 8; ++fd) {
      #pragma unroll
      for (int kt = 0; kt < 2; ++kt) {
        bf16x8 pa = *(const bf16x8*)(&Plds[wave][l15 * 64 + kt * 32 + l4 * 8]);
        bf16x8 vb = *(const bf16x8*)(Vs + (fd * 16 + l15) * 64 + kt * 32 + l4 * 8);
        oacc[fd] = __builtin_amdgcn_mfma_f32_16x16x32_bf16(pa, vb, oacc[fd], 0, 0, 0);
      }
    }
    __syncthreads();
  }
  #pragma unroll
  for (int fd = 0; fd < 8; ++fd) {
    #pragma unroll
    for (int r = 0; r < 4; ++r) {
      const long row = qb * 64 + wave * 16 + l4 * 4 + r;
      outb[row * 4096 + head * 128 + fd * 16 + l15] = (bf16)(oacc[fd][r] / l_r[r]);
    }
  }
}

// ---------------------------------------------------------------------------
extern "C" void kernel_launch(void* const* d_in, const int* in_sizes, int n_in,
                              void* d_out, int out_size, void* d_ws, size_t ws_size,
                              hipStream_t stream) {
  const float* X  = (const float*)d_in[0];
  const float* Wq = (const float*)d_in[1];
  const float* Wk = (const float*)d_in[2];
  const float* Wv = (const float*)d_in[3];
  const float* Wo = (const float*)d_in[4];
  const float* bo = (const float*)d_in[5];
  const float* g1 = (const float*)d_in[6];
  const float* g2 = (const float*)d_in[7];
  const float* W1 = (const float*)d_in[8];
  const float* W2 = (const float*)d_in[9];
  const float* W3 = (const float*)d_in[10];
  float* out = (float*)d_out;

  hipFuncSetAttribute((const void*)gemmd<256, 3>, hipFuncAttributeMaxDynamicSharedMemorySize, 131072);
  hipFuncSetAttribute((const void*)gemmd<256, 4>, hipFuncAttributeMaxDynamicSharedMemorySize, 131072);
  hipFuncSetAttribute((const void*)gemmd<128, 1>, hipFuncAttributeMaxDynamicSharedMemorySize, 98304);
  hipFuncSetAttribute((const void*)gemmd<128, 2>, hipFuncAttributeMaxDynamicSharedMemorySize, 98304);

  char* p = (char*)d_ws;
  auto alloc = [&](size_t bytes) {
    char* r = p;
    p += (bytes + 255) & ~(size_t)255;
    return r;
  };
  float* cosT = (float*)alloc(2048 * 64 * 4);
  float* sinT = (float*)alloc(2048 * 64 * 4);
  bf16* WqkvT = (bf16*)alloc(12288L * 4096 * 2);   // [12288][4096]; later g
  bf16* WoT  = (bf16*)alloc(4096L * 4096 * 2);
  bf16* W12T = (bf16*)alloc(22016L * 4096 * 2);    // interleaved [22016][4096]
  bf16* W3T  = (bf16*)alloc(4096L * 11008 * 2);
  bf16* qhB  = (bf16*)alloc(2048L * 4096 * 2);     // [32][2048][128]
  bf16* khB  = (bf16*)alloc(2048L * 4096 * 2);
  bf16* vtB  = (bf16*)alloc(2048L * 4096 * 2);     // [32][128][2048]
  bf16* hbuf = (bf16*)alloc(2048L * 4096 * 2);     // h, then attnb
  bf16* h2   = (bf16*)alloc(2048L * 4096 * 2);
  float* X2  = (float*)alloc(2048L * 4096 * 4);

  bf16* gsw = (bf16*)WqkvT;   // g [2048][11008] (WqkvT dead after QKV GEMM)
  bf16* attnb = hbuf;

  rope_table_kernel<<<512, 256, 0, stream>>>(cosT, sinT);
  wtrans_kernel<<<dim3(64, 64), 256, 0, stream>>>(Wq, WqkvT, 4096, 4096);
  wtrans_kernel<<<dim3(64, 64), 256, 0, stream>>>(Wk, WqkvT + 4096L * 4096, 4096, 4096);
  wtrans_kernel<<<dim3(64, 64), 256, 0, stream>>>(Wv, WqkvT + 2 * 4096L * 4096, 4096, 4096);
  wtrans_kernel<<<dim3(64, 64), 256, 0, stream>>>(Wo, WoT, 4096, 4096);
  w12trans_kernel<<<dim3(344, 128), 256, 0, stream>>>(W1, W12T, 0);
  w12trans_kernel<<<dim3(344, 128), 256, 0, stream>>>(W2, W12T, 16);
  wtrans_kernel<<<dim3(64, 172), 256, 0, stream>>>(W3, W3T, 11008, 4096);

  rmsnorm_kernel<<<2048, 256, 0, stream>>>(X, g1, hbuf, 4096);

  // q,k,v = rope/reorder(h @ [Wq|Wk|Wv])  — fused epilogue
  gemmd<256, 3><<<384, 256, 131072, stream>>>(hbuf, WqkvT, nullptr, nullptr, nullptr,
                                              cosT, sinT, qhB, khB, vtB,
                                              2048, 12288, 4096, 8);

  attn_kernel<<<dim3(32, 32), 256, 0, stream>>>(qhB, khB, vtB, attnb);

  // X2 = attn @ Wo + bo + X
  gemmd<128, 1><<<256, 256, 98304, stream>>>(attnb, WoT, X2, bo, X,
                                             nullptr, nullptr, nullptr, nullptr, nullptr,
                                             2048, 4096, 4096, 16);

  rmsnorm_kernel<<<2048, 256, 0, stream>>>(X2, g2, h2, 4096);

  // g = silu(h2@W1) * (h2@W2)  — fused epilogue on interleaved W12
  gemmd<256, 4><<<688, 256, 131072, stream>>>(h2, W12T, gsw, nullptr, nullptr,
                                              nullptr, nullptr, nullptr, nullptr, nullptr,
                                              2048, 22016, 4096, 8);

  // out = g @ W3 + X2
  gemmd<128, 2><<<256, 256, 98304, stream>>>(gsw, W3T, out, nullptr, X2,
                                             nullptr, nullptr, nullptr, nullptr, nullptr,
                                             2048, 4096, 11008, 16);
}

// Round 7
// 1372.929 us; speedup vs baseline: 1.1743x; 1.1743x over previous
//
#include <hip/hip_runtime.h>
#include <hip/hip_bf16.h>
#include <cstdint>
#include <cmath>

typedef __bf16 bf16;
typedef __attribute__((ext_vector_type(8))) __bf16 bf16x8;
typedef __attribute__((ext_vector_type(4))) __bf16 bf16x4;
typedef __attribute__((ext_vector_type(4))) float f32x4;

// async global->LDS, 16B per lane, dest = wave-uniform base (+ lane*16 by HW)
__device__ __forceinline__ void gload_lds16(const void* g, void* l) {
  __builtin_amdgcn_global_load_lds((__attribute__((address_space(1))) void*)g,
                                   (__attribute__((address_space(3))) void*)l,
                                   16, 0, 0);
}

// ---------------------------------------------------------------------------
// Drift GEMM (round-5 proven): BM x 256 tile, BK=64, 8 waves (4M x 2N: wave =
// BM/4 rows x 128 cols), double-buffered LDS, ONE __syncthreads per K-tile,
// full-tile prefetch front-loaded (~1 tile of latency hiding), T5 setprio
// around the MFMA cluster. C = A[M,K] @ Bt^T (Bt stored [N][K] bf16).
// LDS: buf*BUFS + {A:0,B:ASZ} + row*128 + (chunk^(row&7))*16 (conflict-free).
// EPI 1: f32 = acc+bias[col]+resid       (Wo)
// EPI 2: f32 = acc+resid                 (W3)
// EPI 3: QKV fused RoPE + head reorder: q,k -> [h][s][128], v -> [h][128][s]
// EPI 4: FF fused SwiGLU on 16-interleaved W1/W2 -> g [s][11008]
// ---------------------------------------------------------------------------
template<int BM, int EPI>
__global__ __launch_bounds__(512, 2) void gemmd(
    const bf16* __restrict__ A, const bf16* __restrict__ Bt, void* __restrict__ Cv,
    const float* __restrict__ bias, const float* __restrict__ resid,
    const float* __restrict__ cosT, const float* __restrict__ sinT,
    bf16* __restrict__ q_out, bf16* __restrict__ k_out, bf16* __restrict__ v_out,
    int M, int N, int K, int gm) {
  extern __shared__ char lds[];
  constexpr int ASZ = BM * 128;      // A region bytes (BM rows x 128B)
  constexpr int BUFS = ASZ + 32768;  // per-buffer stride (B = 256 rows x 128B)
  constexpr int MF = BM / 64;        // m-frags per wave (wave rows = BM/4)
  constexpr int LA = BM / 64;        // A stage loads per thread

  const int tid = threadIdx.x;
  const int wave = tid >> 6, lane = tid & 63;
  const int wr = wave >> 1, wc = wave & 1;   // 4M x 2N wave grid
  const int l15 = lane & 15, l4 = lane >> 4;
  // XCD-aware swizzle (grids are multiples of 8); same-tn octets land on one XCD
  const int qq = gridDim.x >> 3;
  const int wgid = (blockIdx.x & 7) * qq + (blockIdx.x >> 3);
  const int tm = wgid % gm, tn = wgid / gm;
  const long brow = (long)tm * BM, bcol = (long)tn * 256;
  const int NT = K >> 6;
  const bf16* Ab = A + brow * K;
  const bf16* Bb = Bt + bcol * K;

  f32x4 acc[MF][8];
  #pragma unroll
  for (int i = 0; i < MF; ++i)
    #pragma unroll
    for (int j = 0; j < 8; ++j) acc[i][j] = (f32x4){0.f, 0.f, 0.f, 0.f};

  bf16x8 a[MF][2], b[8][2];

  auto stage = [&](int T) {
    const long kofs = (long)T << 6;
    char* wb = lds + (T & 1) * BUFS;
    #pragma unroll
    for (int i = 0; i < LA; ++i) {
      const int slot = i * 512 + tid, r = slot >> 3, c0 = slot & 7;
      gload_lds16(Ab + (long)r * K + kofs + ((c0 ^ (r & 7)) << 3), wb + slot * 16);
    }
    #pragma unroll
    for (int i = 0; i < 4; ++i) {
      const int slot = i * 512 + tid, r = slot >> 3, c0 = slot & 7;
      gload_lds16(Bb + (long)r * K + kofs + ((c0 ^ (r & 7)) << 3), wb + ASZ + slot * 16);
    }
  };

  stage(0);
  __syncthreads();

  for (int g = 0; g < NT; ++g) {
    const int pg = (g & 1) * BUFS;
    if (g + 1 < NT) stage(g + 1);   // writes opposite buffer; fenced by barrier
    #pragma unroll
    for (int nf = 0; nf < 8; ++nf)
      #pragma unroll
      for (int ks = 0; ks < 2; ++ks) {
        const int r = wc * 128 + nf * 16 + l15;
        b[nf][ks] = *(const bf16x8*)(lds + pg + ASZ + r * 128 + (((ks * 4 + l4) ^ (r & 7)) << 4));
      }
    #pragma unroll
    for (int mf = 0; mf < MF; ++mf)
      #pragma unroll
      for (int ks = 0; ks < 2; ++ks) {
        const int r = wr * (BM / 4) + mf * 16 + l15;
        a[mf][ks] = *(const bf16x8*)(lds + pg + r * 128 + (((ks * 4 + l4) ^ (r & 7)) << 4));
      }
    __builtin_amdgcn_s_setprio(1);
    #pragma unroll
    for (int ks = 0; ks < 2; ++ks)
      #pragma unroll
      for (int mf = 0; mf < MF; ++mf)
        #pragma unroll
        for (int nf = 0; nf < 8; ++nf)
          acc[mf][nf] = __builtin_amdgcn_mfma_f32_16x16x32_bf16(
              a[mf][ks], b[nf][ks], acc[mf][nf], 0, 0, 0);
    __builtin_amdgcn_s_setprio(0);
    __syncthreads();
  }

  // ------------------------------- epilogues -------------------------------
  if (EPI == 1 || EPI == 2) {
    #pragma unroll
    for (int mf = 0; mf < MF; ++mf) {
      const long row0 = brow + wr * (BM / 4) + mf * 16 + l4 * 4;
      #pragma unroll
      for (int nf = 0; nf < 8; ++nf) {
        const long col = bcol + wc * 128 + nf * 16 + l15;
        #pragma unroll
        for (int rj = 0; rj < 4; ++rj) {
          const long idx = (row0 + rj) * N + col;
          const float v = acc[mf][nf][rj];
          if (EPI == 1) ((float*)Cv)[idx] = v + bias[col] + resid[idx];
          else          ((float*)Cv)[idx] = v + resid[idx];
        }
      }
    }
  } else if (EPI == 3) {
    const int region = (int)(bcol >> 12);           // 0=Q, 1=K, 2=V
    const int hc = (int)(bcol & 4095) + wc * 128;   // head-space col base
    const int h = hc >> 7;
    if (region < 2) {
      bf16* dh = (region == 0 ? q_out : k_out) + (long)h * 2048 * 128;
      #pragma unroll
      for (int mf = 0; mf < MF; ++mf) {
        #pragma unroll
        for (int rj = 0; rj < 4; ++rj) {
          const int s = (int)brow + wr * (BM / 4) + mf * 16 + l4 * 4 + rj;
          const float* cr = cosT + s * 64;
          const float* sr = sinT + s * 64;
          #pragma unroll
          for (int nfp = 0; nfp < 4; ++nfp) {
            const int d = nfp * 16 + l15;
            const float c = cr[d], sn = sr[d];
            const float x1 = acc[mf][nfp][rj], x2 = acc[mf][nfp + 4][rj];
            dh[(long)s * 128 + d]      = (bf16)(x1 * c - x2 * sn);
            dh[(long)s * 128 + d + 64] = (bf16)(x2 * c + x1 * sn);
          }
        }
      }
    } else {
      bf16* dh = v_out + (long)h * 128 * 2048;
      #pragma unroll
      for (int mf = 0; mf < MF; ++mf) {
        const int s0 = (int)brow + wr * (BM / 4) + mf * 16 + l4 * 4;
        #pragma unroll
        for (int nf = 0; nf < 8; ++nf) {
          const int d = nf * 16 + l15;
          bf16x4 v;
          #pragma unroll
          for (int rj = 0; rj < 4; ++rj) v[rj] = (bf16)acc[mf][nf][rj];
          *(bf16x4*)(dh + (long)d * 2048 + s0) = v;
        }
      }
    }
  } else {  // EPI == 4: fused SwiGLU, interleaved W12 columns -> g [s][11008]
    #pragma unroll
    for (int mf = 0; mf < MF; ++mf) {
      #pragma unroll
      for (int rj = 0; rj < 4; ++rj) {
        const int s = (int)brow + wr * (BM / 4) + mf * 16 + l4 * 4 + rj;
        bf16* gr = (bf16*)Cv + (long)s * 11008;
        #pragma unroll
        for (int nfp = 0; nfp < 4; ++nfp) {
          const int col = (int)bcol + wc * 128 + nfp * 32 + l15;
          const int j = ((col >> 5) << 4) + l15;
          const float x1 = acc[mf][2 * nfp][rj], x2 = acc[mf][2 * nfp + 1][rj];
          const float sg = x1 / (1.f + __expf(-x1));
          gr[j] = (bf16)(sg * x2);
        }
      }
    }
  }
}

// ---------------------------------------------------------------------------
// RMSNorm: one block per row of [2048][4096] f32 -> bf16
// ---------------------------------------------------------------------------
__global__ __launch_bounds__(256) void rmsnorm_kernel(
    const float* __restrict__ X, const float* __restrict__ gamma,
    bf16* __restrict__ out, int D) {
  const int row = blockIdx.x;
  const float* xr = X + (long)row * D;
  float ss = 0.f;
  for (int i = threadIdx.x * 4; i < D; i += 1024) {
    float4 v = *(const float4*)(xr + i);
    ss += v.x * v.x + v.y * v.y + v.z * v.z + v.w * v.w;
  }
  #pragma unroll
  for (int off = 32; off; off >>= 1) ss += __shfl_down(ss, off, 64);
  __shared__ float wsum[4];
  if ((threadIdx.x & 63) == 0) wsum[threadIdx.x >> 6] = ss;
  __syncthreads();
  const float tot = wsum[0] + wsum[1] + wsum[2] + wsum[3];
  const float scale = rsqrtf(1e-7f + tot / (float)D);
  bf16* orow = out + (long)row * D;
  for (int i = threadIdx.x * 4; i < D; i += 1024) {
    float4 v = *(const float4*)(xr + i);
    float4 g = *(const float4*)(gamma + i);
    orow[i]     = (bf16)(v.x * scale * g.x);
    orow[i + 1] = (bf16)(v.y * scale * g.y);
    orow[i + 2] = (bf16)(v.z * scale * g.z);
    orow[i + 3] = (bf16)(v.w * scale * g.w);
  }
}

// ---------------------------------------------------------------------------
// Vectorized weight transpose + f32->bf16: in [R][C] f32 -> out [C][R] bf16.
// 64x64 tile; float4 loads (16B/lane), bf16x4 stores (8B/lane).
// ---------------------------------------------------------------------------
__global__ __launch_bounds__(256) void wtrans_kernel(
    const float* __restrict__ in, bf16* __restrict__ out, int R, int C) {
  __shared__ float t[64][65];
  const int bx = blockIdx.x, by = blockIdx.y;  // bx: C-tile, by: R-tile
  const int lr = threadIdx.x >> 4;             // 0..15
  const int lc4 = (threadIdx.x & 15) * 4;
  #pragma unroll
  for (int i = 0; i < 4; ++i) {
    const int r = lr + i * 16;
    const float4 v = *(const float4*)(in + (long)(by * 64 + r) * C + bx * 64 + lc4);
    t[r][lc4] = v.x; t[r][lc4 + 1] = v.y; t[r][lc4 + 2] = v.z; t[r][lc4 + 3] = v.w;
  }
  __syncthreads();
  const int oc = threadIdx.x >> 4;
  const int or4 = (threadIdx.x & 15) * 4;
  #pragma unroll
  for (int i = 0; i < 4; ++i) {
    const int c = oc + i * 16;
    bf16x4 v;
    #pragma unroll
    for (int j = 0; j < 4; ++j) v[j] = (bf16)t[or4 + j][c];
    *(bf16x4*)(out + (long)(bx * 64 + c) * R + by * 64 + or4) = v;
  }
}

// ---------------------------------------------------------------------------
// Vectorized W1/W2 interleaved transpose: in [4096][11008] f32, col j ->
// out row ((j>>4)<<5)+off+(j&15) (off: W1=0, W2=16), cols = k (4096) bf16.
// 64x64 tile: bx: j-tiles (172), by: k-tiles (64).
// ---------------------------------------------------------------------------
__global__ __launch_bounds__(256) void w12trans_kernel(
    const float* __restrict__ in, bf16* __restrict__ out, int off) {
  __shared__ float t[64][65];   // [k_local][j_local]
  const int bx = blockIdx.x, by = blockIdx.y;
  const int lk = threadIdx.x >> 4;
  const int lj4 = (threadIdx.x & 15) * 4;
  #pragma unroll
  for (int i = 0; i < 4; ++i) {
    const int k = lk + i * 16;
    const float4 v = *(const float4*)(in + (long)(by * 64 + k) * 11008 + bx * 64 + lj4);
    t[k][lj4] = v.x; t[k][lj4 + 1] = v.y; t[k][lj4 + 2] = v.z; t[k][lj4 + 3] = v.w;
  }
  __syncthreads();
  const int oj = threadIdx.x >> 4;
  const int ok4 = (threadIdx.x & 15) * 4;
  #pragma unroll
  for (int i = 0; i < 4; ++i) {
    const int j = bx * 64 + oj + i * 16;
    const int r = ((j >> 4) << 5) + off + (j & 15);
    bf16x4 v;
    #pragma unroll
    for (int jj = 0; jj < 4; ++jj) v[jj] = (bf16)t[ok4 + jj][oj + i * 16];
    *(bf16x4*)(out + (long)r * 4096 + by * 64 + ok4) = v;
  }
}

// ---------------------------------------------------------------------------
__global__ __launch_bounds__(256) void rope_table_kernel(float* __restrict__ cosT,
                                                         float* __restrict__ sinT) {
  const int idx = blockIdx.x * 256 + threadIdx.x;
  const int i = idx & 63, s = idx >> 6;
  const float inv = powf(10000.f, -(float)i / 64.f);
  const float ang = (float)s * inv;
  cosT[idx] = cosf(ang);
  sinT[idx] = sinf(ang);
}

// ---------------------------------------------------------------------------
// Flash attention, causal. Block=(qb,head), 4 waves x 16 q-rows.
// ---------------------------------------------------------------------------
__global__ __launch_bounds__(256) void attn_kernel(
    const bf16* __restrict__ qh, const bf16* __restrict__ kh,
    const bf16* __restrict__ vt, bf16* __restrict__ outb) {
  constexpr int S = 2048;
  const int qb = blockIdx.x, head = blockIdx.y;
  const int tid = threadIdx.x, wave = tid >> 6, lane = tid & 63;
  __shared__ bf16 Ks[64 * 128];
  __shared__ bf16 Vs[128 * 64];
  __shared__ bf16 Plds[4][16 * 64];
  const bf16* qhh = qh + (long)head * S * 128;
  const bf16* khh = kh + (long)head * S * 128;
  const bf16* vth = vt + (long)head * 128 * S;

  const int l15 = lane & 15, l4 = lane >> 4;
  const int qrow = qb * 64 + wave * 16 + l15;
  bf16x8 qf[4];
  #pragma unroll
  for (int kf = 0; kf < 4; ++kf)
    qf[kf] = *(const bf16x8*)(qhh + (long)qrow * 128 + kf * 32 + l4 * 8);

  float m_r[4], l_r[4];
  #pragma unroll
  for (int r = 0; r < 4; ++r) { m_r[r] = -INFINITY; l_r[r] = 0.f; }
  f32x4 oacc[8] = {};
  const float scale = 0.08838834764831845f;

  for (int tb = 0; tb <= qb; ++tb) {
    #pragma unroll
    for (int i = 0; i < 4; ++i) {
      const int c = wave + 4 * i;
      gload_lds16(khh + (long)(tb * 64 + c * 4 + l4) * 128 + l15 * 8, Ks + c * 512);
      gload_lds16(vth + (long)(c * 8 + (lane >> 3)) * S + tb * 64 + (lane & 7) * 8, Vs + c * 512);
    }
    __syncthreads();

    f32x4 sf[4];
    #pragma unroll
    for (int ft = 0; ft < 4; ++ft) {
      f32x4 acn = {};
      #pragma unroll
      for (int kf = 0; kf < 4; ++kf) {
        bf16x8 kfr = *(const bf16x8*)(Ks + (ft * 16 + l15) * 128 + kf * 32 + l4 * 8);
        acn = __builtin_amdgcn_mfma_f32_16x16x32_bf16(qf[kf], kfr, acn, 0, 0, 0);
      }
      #pragma unroll
      for (int r = 0; r < 4; ++r) sf[ft][r] = acn[r] * scale;
    }
    if (tb == qb) {
      #pragma unroll
      for (int ft = 0; ft < 4; ++ft) {
        const int t_l = ft * 16 + l15;
        #pragma unroll
        for (int r = 0; r < 4; ++r)
          if (t_l > wave * 16 + l4 * 4 + r) sf[ft][r] = -INFINITY;
      }
    }
    float scl[4];
    #pragma unroll
    for (int r = 0; r < 4; ++r) {
      float mx = fmaxf(fmaxf(sf[0][r], sf[1][r]), fmaxf(sf[2][r], sf[3][r]));
      mx = fmaxf(mx, __shfl_xor(mx, 1, 64));
      mx = fmaxf(mx, __shfl_xor(mx, 2, 64));
      mx = fmaxf(mx, __shfl_xor(mx, 4, 64));
      mx = fmaxf(mx, __shfl_xor(mx, 8, 64));
      const float mnew = fmaxf(m_r[r], mx);
      scl[r] = __expf(m_r[r] - mnew);
      m_r[r] = mnew;
      float rs = 0.f;
      #pragma unroll
      for (int ft = 0; ft < 4; ++ft) {
        const float pexp = __expf(sf[ft][r] - mnew);
        sf[ft][r] = pexp;
        rs += pexp;
      }
      rs += __shfl_xor(rs, 1, 64);
      rs += __shfl_xor(rs, 2, 64);
      rs += __shfl_xor(rs, 4, 64);
      rs += __shfl_xor(rs, 8, 64);
      l_r[r] = l_r[r] * scl[r] + rs;
    }
    #pragma unroll
    for (int ft = 0; ft < 4; ++ft)
      #pragma unroll
      for (int r = 0; r < 4; ++r)
        Plds[wave][(l4 * 4 + r) * 64 + ft * 16 + l15] = (bf16)sf[ft][r];
    #pragma unroll
    for (int fd = 0; fd < 8; ++fd)
      #pragma unroll
      for (int r = 0; r < 4; ++r) oacc[fd][r] *= scl[r];
    #pragma unroll
    for (int fd = 0; fd < 8; ++fd) {
      #pragma unroll
      for (int kt = 0; kt < 2; ++kt) {
        bf16x8 pa = *(const bf16x8*)(&Plds[wave][l15 * 64 + kt * 32 + l4 * 8]);
        bf16x8 vb = *(const bf16x8*)(Vs + (fd * 16 + l15) * 64 + kt * 32 + l4 * 8);
        oacc[fd] = __builtin_amdgcn_mfma_f32_16x16x32_bf16(pa, vb, oacc[fd], 0, 0, 0);
      }
    }
    __syncthreads();
  }
  #pragma unroll
  for (int fd = 0; fd < 8; ++fd) {
    #pragma unroll
    for (int r = 0; r < 4; ++r) {
      const long row = qb * 64 + wave * 16 + l4 * 4 + r;
      outb[row * 4096 + head * 128 + fd * 16 + l15] = (bf16)(oacc[fd][r] / l_r[r]);
    }
  }
}

// ---------------------------------------------------------------------------
extern "C" void kernel_launch(void* const* d_in, const int* in_sizes, int n_in,
                              void* d_out, int out_size, void* d_ws, size_t ws_size,
                              hipStream_t stream) {
  const float* X  = (const float*)d_in[0];
  const float* Wq = (const float*)d_in[1];
  const float* Wk = (const float*)d_in[2];
  const float* Wv = (const float*)d_in[3];
  const float* Wo = (const float*)d_in[4];
  const float* bo = (const float*)d_in[5];
  const float* g1 = (const float*)d_in[6];
  const float* g2 = (const float*)d_in[7];
  const float* W1 = (const float*)d_in[8];
  const float* W2 = (const float*)d_in[9];
  const float* W3 = (const float*)d_in[10];
  float* out = (float*)d_out;

  hipFuncSetAttribute((const void*)gemmd<256, 3>, hipFuncAttributeMaxDynamicSharedMemorySize, 131072);
  hipFuncSetAttribute((const void*)gemmd<256, 4>, hipFuncAttributeMaxDynamicSharedMemorySize, 131072);
  hipFuncSetAttribute((const void*)gemmd<128, 1>, hipFuncAttributeMaxDynamicSharedMemorySize, 98304);
  hipFuncSetAttribute((const void*)gemmd<128, 2>, hipFuncAttributeMaxDynamicSharedMemorySize, 98304);

  char* p = (char*)d_ws;
  auto alloc = [&](size_t bytes) {
    char* r = p;
    p += (bytes + 255) & ~(size_t)255;
    return r;
  };
  float* cosT = (float*)alloc(2048 * 64 * 4);
  float* sinT = (float*)alloc(2048 * 64 * 4);
  bf16* WqkvT = (bf16*)alloc(12288L * 4096 * 2);   // [12288][4096]; later g
  bf16* WoT  = (bf16*)alloc(4096L * 4096 * 2);
  bf16* W12T = (bf16*)alloc(22016L * 4096 * 2);    // interleaved [22016][4096]
  bf16* W3T  = (bf16*)alloc(4096L * 11008 * 2);
  bf16* qhB  = (bf16*)alloc(2048L * 4096 * 2);     // [32][2048][128]
  bf16* khB  = (bf16*)alloc(2048L * 4096 * 2);
  bf16* vtB  = (bf16*)alloc(2048L * 4096 * 2);     // [32][128][2048]
  bf16* hbuf = (bf16*)alloc(2048L * 4096 * 2);     // h, then attnb
  bf16* h2   = (bf16*)alloc(2048L * 4096 * 2);
  float* X2  = (float*)alloc(2048L * 4096 * 4);

  bf16* gsw = (bf16*)WqkvT;   // g [2048][11008] (WqkvT dead after QKV GEMM)
  bf16* attnb = hbuf;

  rope_table_kernel<<<512, 256, 0, stream>>>(cosT, sinT);
  wtrans_kernel<<<dim3(64, 64), 256, 0, stream>>>(Wq, WqkvT, 4096, 4096);
  wtrans_kernel<<<dim3(64, 64), 256, 0, stream>>>(Wk, WqkvT + 4096L * 4096, 4096, 4096);
  wtrans_kernel<<<dim3(64, 64), 256, 0, stream>>>(Wv, WqkvT + 2 * 4096L * 4096, 4096, 4096);
  wtrans_kernel<<<dim3(64, 64), 256, 0, stream>>>(Wo, WoT, 4096, 4096);
  w12trans_kernel<<<dim3(172, 64), 256, 0, stream>>>(W1, W12T, 0);
  w12trans_kernel<<<dim3(172, 64), 256, 0, stream>>>(W2, W12T, 16);
  wtrans_kernel<<<dim3(64, 172), 256, 0, stream>>>(W3, W3T, 11008, 4096);

  rmsnorm_kernel<<<2048, 256, 0, stream>>>(X, g1, hbuf, 4096);

  // q,k,v = rope/reorder(h @ [Wq|Wk|Wv])  — fused epilogue
  gemmd<256, 3><<<384, 512, 131072, stream>>>(hbuf, WqkvT, nullptr, nullptr, nullptr,
                                              cosT, sinT, qhB, khB, vtB,
                                              2048, 12288, 4096, 8);

  attn_kernel<<<dim3(32, 32), 256, 0, stream>>>(qhB, khB, vtB, attnb);

  // X2 = attn @ Wo + bo + X
  gemmd<128, 1><<<256, 512, 98304, stream>>>(attnb, WoT, X2, bo, X,
                                             nullptr, nullptr, nullptr, nullptr, nullptr,
                                             2048, 4096, 4096, 16);

  rmsnorm_kernel<<<2048, 256, 0, stream>>>(X2, g2, h2, 4096);

  // g = silu(h2@W1) * (h2@W2)  — fused epilogue on interleaved W12
  gemmd<256, 4><<<688, 512, 131072, stream>>>(h2, W12T, gsw, nullptr, nullptr,
                                              nullptr, nullptr, nullptr, nullptr, nullptr,
                                              2048, 22016, 4096, 8);

  // out = g @ W3 + X2
  gemmd<128, 2><<<256, 512, 98304, stream>>>(gsw, W3T, out, nullptr, X2,
                                             nullptr, nullptr, nullptr, nullptr, nullptr,
                                             2048, 4096, 11008, 16);
}